// Round 2
// baseline (7514.582 us; speedup 1.0000x reference)
//
#include <hip/hip_runtime.h>
#include <stdint.h>

#define T_LEN 1024
#define BATCH 32
#define DIN   512
#define HID   512
#define G3    1536          // 3*HID
#define ROWS  (T_LEN*BATCH) // 32768
#define NSL   8             // h-slices (blocks) per direction
#define FSTR  16            // flag stride in ints (64B cacheline)

typedef short bf16x8 __attribute__((ext_vector_type(8)));
typedef float f32x4  __attribute__((ext_vector_type(4)));

__device__ __forceinline__ unsigned short f2bf(float f) {
  union { float f; uint32_t u; } v; v.f = f;
  uint32_t u = v.u;
  return (unsigned short)((u + 0x7fffu + ((u >> 16) & 1u)) >> 16);  // RNE
}
__device__ __forceinline__ float bf2f(unsigned short h) {
  union { uint32_t u; float f; } v; v.u = ((uint32_t)h) << 16; return v.f;
}
__device__ __forceinline__ float sigm(float x)   { return 1.f / (1.f + __expf(-x)); }
__device__ __forceinline__ float tanh_f(float x) { return 2.f / (1.f + __expf(-2.f * x)) - 1.f; }

// ---------------- zero init (stats + flags) ----------------
__global__ void zero_init(float* stats, int* flags) {
  int i = blockIdx.x * 256 + threadIdx.x;     // grid 1024 -> 262144 threads
  flags[i] = 0;                               // 2*1024*8*16 = 262144 ints
  if (i < 2 * G3) stats[i] = 0.f;
}

// ---------------- f32 -> bf16 convert ----------------
__global__ void convert_bf16(const float* __restrict__ src, unsigned short* __restrict__ dst, int n4) {
  int i = blockIdx.x * 256 + threadIdx.x;
  if (i < n4) {
    float4 v = ((const float4*)src)[i];
    ushort4 o;
    o.x = f2bf(v.x); o.y = f2bf(v.y); o.z = f2bf(v.z); o.w = f2bf(v.w);
    ((ushort4*)dst)[i] = o;
  }
}

// ---------------- P = x @ Wx^T  (bf16 in, bf16 out, fp32 acc) ----------------
__global__ __launch_bounds__(256) void gemm_proj(const unsigned short* __restrict__ xb,
                                                 const unsigned short* __restrict__ wxb,
                                                 unsigned short* __restrict__ P) {
  int w = threadIdx.x >> 6;
  int l = threadIdx.x & 63;
  int mi = w >> 1, ni = w & 1;
  int row_base = blockIdx.x * 64 + mi * 32;
  int col_base = blockIdx.y * 64 + ni * 32;
  int lr = l & 15, lk8 = (l >> 4) * 8;
  f32x4 acc00 = {0,0,0,0}, acc01 = {0,0,0,0}, acc10 = {0,0,0,0}, acc11 = {0,0,0,0};
  #pragma unroll 4
  for (int kk = 0; kk < 16; ++kk) {
    int k0 = kk * 32 + lk8;
    bf16x8 a0 = *(const bf16x8*)(xb  + (size_t)(row_base + lr) * DIN + k0);
    bf16x8 a1 = *(const bf16x8*)(xb  + (size_t)(row_base + 16 + lr) * DIN + k0);
    bf16x8 b0 = *(const bf16x8*)(wxb + (size_t)(col_base + lr) * DIN + k0);
    bf16x8 b1 = *(const bf16x8*)(wxb + (size_t)(col_base + 16 + lr) * DIN + k0);
    acc00 = __builtin_amdgcn_mfma_f32_16x16x32_bf16(a0, b0, acc00, 0, 0, 0);
    acc01 = __builtin_amdgcn_mfma_f32_16x16x32_bf16(a0, b1, acc01, 0, 0, 0);
    acc10 = __builtin_amdgcn_mfma_f32_16x16x32_bf16(a1, b0, acc10, 0, 0, 0);
    acc11 = __builtin_amdgcn_mfma_f32_16x16x32_bf16(a1, b1, acc11, 0, 0, 0);
  }
  int rrow = (l >> 4) * 4;
  #pragma unroll
  for (int r = 0; r < 4; ++r) {
    P[(size_t)(row_base +      rrow + r) * G3 + col_base +      lr] = f2bf(acc00[r]);
    P[(size_t)(row_base +      rrow + r) * G3 + col_base + 16 + lr] = f2bf(acc01[r]);
    P[(size_t)(row_base + 16 + rrow + r) * G3 + col_base +      lr] = f2bf(acc10[r]);
    P[(size_t)(row_base + 16 + rrow + r) * G3 + col_base + 16 + lr] = f2bf(acc11[r]);
  }
}

// ---------------- per-channel sums over rows ----------------
__global__ void bn_stats(const unsigned short* __restrict__ P, float* __restrict__ stats) {
  int col = blockIdx.x * 256 + threadIdx.x;   // grid.x = 6  -> 1536 cols
  int r0  = blockIdx.y * 512;                 // grid.y = 64 -> 32768 rows
  float s = 0.f, q = 0.f;
  for (int r = 0; r < 512; ++r) {
    float v = bf2f(P[(size_t)(r0 + r) * G3 + col]);
    s += v; q += v * v;
  }
  atomicAdd(&stats[col], s);
  atomicAdd(&stats[G3 + col], q);
}

// ---------------- fold BN into scale/shift ----------------
__global__ void bn_final(const float* __restrict__ stats, const float* __restrict__ gamma,
                         const float* __restrict__ beta, float* __restrict__ params) {
  int c = blockIdx.x * 256 + threadIdx.x;
  if (c >= G3) return;
  float mean = stats[c] * (1.f / ROWS);
  float var  = stats[G3 + c] * (1.f / ROWS) - mean * mean;
  float sc = gamma[c] * rsqrtf(var + 1e-5f);
  params[c] = sc;
  params[G3 + c] = beta[c] - mean * sc;
}

// ---------------- the bidirectional GRU scan ----------------
// 16 blocks: [0,8) forward, [8,16) backward. Block owns h-cols [s*64, s*64+64)
// => 192 hp columns (3 gates x 64). 256 threads = 4 waves; wave w holds 3
// register-resident 16-col Wh panels (48 bf16x8 = 192 VGPR) and computes
// M=32 x N=48 of hp per step (96 MFMA). Cross-block h broadcast via global
// hist + per-block release flags in distinct cachelines (no RMW contention).
__global__ __launch_bounds__(256, 1) void scan_kernel(
    const unsigned short* __restrict__ P, const float* __restrict__ params,
    const unsigned short* __restrict__ whf, const unsigned short* __restrict__ whb,
    unsigned short* __restrict__ histf, unsigned short* __restrict__ histb,
    int* __restrict__ flags) {
  int blk = blockIdx.x;
  int d = blk >> 3;          // direction
  int s = blk & 7;           // slice
  int j0 = s * 64;           // first owned h column
  int tid = threadIdx.x;
  int w = tid >> 6, l = tid & 63;
  int lr = l & 15, lk8 = (l >> 4) * 8;

  const unsigned short* wh = d ? whb : whf;
  unsigned short* myhist = d ? histb : histf;
  int* myflags = flags + (size_t)d * T_LEN * NSL * FSTR;

  // B fragments: wave w owns hp-col tiles i = w*3+q (q=0..2);
  // tile i -> gate g = i>>2, sub n = i&3, cols cb = g*512 + j0 + n*16.
  bf16x8 bfrag[3][16];
  #pragma unroll
  for (int q = 0; q < 3; ++q) {
    int i = w * 3 + q;
    int cb = (i >> 2) * HID + j0 + (i & 3) * 16;
    const unsigned short* wrow = wh + (size_t)(cb + lr) * HID;
    #pragma unroll
    for (int kk = 0; kk < 16; ++kk)
      bfrag[q][kk] = *(const bf16x8*)(wrow + kk * 32 + lk8);
  }

  __shared__ __align__(16) char hlds[BATCH * HID * 2];  // 32 KB XOR-swizzled h_prev
  __shared__ float hp[3][BATCH][65];                    // padded: kills 4-way write conflict

  // epilogue mapping: element e = tid + i*256 -> b = (tid>>6)+i*4, jj = tid&63
  int jj = tid & 63;
  int jc = j0 + jj;                       // global h column this thread finalizes
  float scr = params[jc],            shr = params[G3 + jc];
  float scz = params[HID + jc],      shz = params[G3 + HID + jc];
  float scn = params[2 * HID + jc],  shn = params[G3 + 2 * HID + jc];

  for (int t = 0; t < T_LEN; ++t) {
    int time = d ? (T_LEN - 1 - t) : t;

    // ---- prefetch this step's x-projection values (h-independent) ----
    float xr[8], xz[8], xn[8];
    #pragma unroll
    for (int i = 0; i < 8; ++i) {
      int b = (tid >> 6) + i * 4;
      const unsigned short* prow = P + (size_t)(time * BATCH + b) * G3 + jc;
      xr[i] = bf2f(prow[0]);
      xz[i] = bf2f(prow[HID]);
      xn[i] = bf2f(prow[2 * HID]);
    }

    // ---- wait for all 8 producer flags of step t-1, then stage h ----
    if (t > 0) {
      if (tid < NSL) {
        int guard = 0;
        while (__hip_atomic_load(myflags + (size_t)(t - 1) * NSL * FSTR + tid * FSTR,
                                 __ATOMIC_RELAXED, __HIP_MEMORY_SCOPE_AGENT) == 0) {
          __builtin_amdgcn_s_sleep(2);
          if (++guard > (1 << 17)) break;   // bailout: wrong answer beats a hang
        }
      }
      __syncthreads();
      // acquire (buffer_inv) so remote XCDs' h writes are visible
      (void)__hip_atomic_load(myflags + (size_t)(t - 1) * NSL * FSTR + (tid & 7) * FSTR,
                              __ATOMIC_ACQUIRE, __HIP_MEMORY_SCOPE_AGENT);
      const unsigned short* hprev = myhist + (size_t)(t - 1) * BATCH * HID;
      #pragma unroll
      for (int i = 0; i < 8; ++i) {
        int c = tid + i * 256;              // 2048 chunks of 16B
        bf16x8 v = *(const bf16x8*)((const char*)hprev + c * 16);
        int row = c >> 6;
        *(bf16x8*)(hlds + ((c * 16) ^ ((row & 7) << 4))) = v;
      }
    } else {
      bf16x8 z = {0, 0, 0, 0, 0, 0, 0, 0};
      #pragma unroll
      for (int i = 0; i < 8; ++i) {
        int c = tid + i * 256;
        *(bf16x8*)(hlds + c * 16) = z;
      }
    }
    __syncthreads();

    // ---- hp = h_prev @ Wh_slice^T : M=32, N=48/wave, K=512 ----
    f32x4 acc[2][3] = {};
    #pragma unroll
    for (int kk = 0; kk < 16; ++kk) {
      int cbase = kk * 64 + lk8 * 2;
      int sw = (lr & 7) << 4;               // (lr+16)&7 == lr&7
      bf16x8 a0 = *(const bf16x8*)(hlds + ((lr * 1024 + cbase) ^ sw));
      bf16x8 a1 = *(const bf16x8*)(hlds + (((lr + 16) * 1024 + cbase) ^ sw));
      #pragma unroll
      for (int q = 0; q < 3; ++q) {
        acc[0][q] = __builtin_amdgcn_mfma_f32_16x16x32_bf16(a0, bfrag[q][kk], acc[0][q], 0, 0, 0);
        acc[1][q] = __builtin_amdgcn_mfma_f32_16x16x32_bf16(a1, bfrag[q][kk], acc[1][q], 0, 0, 0);
      }
    }
    // D layout: row = (l>>4)*4 + r, col = l&15
    #pragma unroll
    for (int q = 0; q < 3; ++q) {
      int i = w * 3 + q;
      int g = i >> 2, ncol = (i & 3) * 16 + lr;
      #pragma unroll
      for (int m = 0; m < 2; ++m) {
        int rrow = m * 16 + (l >> 4) * 4;
        #pragma unroll
        for (int r = 0; r < 4; ++r) hp[g][rrow + r][ncol] = acc[m][q][r];
      }
    }
    __syncthreads();

    // ---- gates + h update for own 64 cols x 32 batch ----
    unsigned short* hout = myhist + (size_t)t * BATCH * HID;
    #pragma unroll
    for (int i = 0; i < 8; ++i) {
      int b = (tid >> 6) + i * 4;
      float rv = sigm(fmaf(xr[i], scr, shr) + hp[0][b][jj]);
      float zv = sigm(fmaf(xz[i], scz, shz) + hp[1][b][jj]);
      float nv = tanh_f(fmaf(xn[i], scn, shn) + rv * hp[2][b][jj]);
      float hold = bf2f(*(const unsigned short*)(hlds + ((b * 1024 + jc * 2) ^ ((b & 7) << 4))));
      hout[b * HID + jc] = f2bf((1.f - zv) * hold + zv * nv);
    }
    __syncthreads();   // all hist writes drained (syncthreads waits vmcnt 0)
    if (tid == 0)
      __hip_atomic_store(myflags + (size_t)t * NSL * FSTR + s * FSTR, 1,
                         __ATOMIC_RELEASE, __HIP_MEMORY_SCOPE_AGENT);
  }
}

// ---------------- out[t] = fwd[t] + bwd[T-1-t] ----------------
__global__ void final_add(const unsigned short* __restrict__ histf,
                          const unsigned short* __restrict__ histb,
                          float* __restrict__ out) {
  size_t i4 = (size_t)blockIdx.x * 256 + threadIdx.x;
  size_t e = i4 * 4;
  int t = (int)(e / (BATCH * HID));
  size_t rem = e % (BATCH * HID);
  ushort4 vf = *(const ushort4*)(histf + e);
  ushort4 vb = *(const ushort4*)(histb + (size_t)(T_LEN - 1 - t) * BATCH * HID + rem);
  float4 o;
  o.x = bf2f(vf.x) + bf2f(vb.x);
  o.y = bf2f(vf.y) + bf2f(vb.y);
  o.z = bf2f(vf.z) + bf2f(vb.z);
  o.w = bf2f(vf.w) + bf2f(vb.w);
  *(float4*)(out + e) = o;
}

extern "C" void kernel_launch(void* const* d_in, const int* in_sizes, int n_in,
                              void* d_out, int out_size, void* d_ws, size_t ws_size,
                              hipStream_t stream) {
  const float* x     = (const float*)d_in[0];
  const float* Wx    = (const float*)d_in[1];
  const float* Whf   = (const float*)d_in[2];
  const float* Whb   = (const float*)d_in[3];
  const float* gamma = (const float*)d_in[4];
  const float* beta  = (const float*)d_in[5];
  float* out = (float*)d_out;

  char* ws = (char*)d_ws;
  size_t off = 0;
  auto alloc = [&](size_t bytes) {
    char* p = ws + off;
    off += (bytes + 255) & ~(size_t)255;
    return p;
  };
  unsigned short* xb    = (unsigned short*)alloc((size_t)ROWS * DIN * 2);
  unsigned short* wxb   = (unsigned short*)alloc((size_t)G3 * DIN * 2);
  unsigned short* whfb  = (unsigned short*)alloc((size_t)G3 * HID * 2);
  unsigned short* whbb  = (unsigned short*)alloc((size_t)G3 * HID * 2);
  unsigned short* P     = (unsigned short*)alloc((size_t)ROWS * G3 * 2);
  float* stats          = (float*)alloc(2 * G3 * 4);
  float* params         = (float*)alloc(2 * G3 * 4);
  unsigned short* histf = (unsigned short*)alloc((size_t)T_LEN * BATCH * HID * 2);
  unsigned short* histb = (unsigned short*)alloc((size_t)T_LEN * BATCH * HID * 2);
  int* flags            = (int*)alloc((size_t)2 * T_LEN * NSL * FSTR * 4);

  hipLaunchKernelGGL(zero_init, dim3(1024), dim3(256), 0, stream, stats, flags);
  hipLaunchKernelGGL(convert_bf16, dim3(16384), dim3(256), 0, stream, x, xb, ROWS * DIN / 4);
  hipLaunchKernelGGL(convert_bf16, dim3(768), dim3(256), 0, stream, Wx, wxb, G3 * DIN / 4);
  hipLaunchKernelGGL(convert_bf16, dim3(768), dim3(256), 0, stream, Whf, whfb, G3 * HID / 4);
  hipLaunchKernelGGL(convert_bf16, dim3(768), dim3(256), 0, stream, Whb, whbb, G3 * HID / 4);
  hipLaunchKernelGGL(gemm_proj, dim3(512, 24), dim3(256), 0, stream, xb, wxb, P);
  hipLaunchKernelGGL(bn_stats, dim3(6, 64), dim3(256), 0, stream, P, stats);
  hipLaunchKernelGGL(bn_final, dim3(6), dim3(256), 0, stream, stats, gamma, beta, params);
  hipLaunchKernelGGL(scan_kernel, dim3(16), dim3(256), 0, stream,
                     P, params, whfb, whbb, histf, histb, flags);
  hipLaunchKernelGGL(final_add, dim3(16384), dim3(256), 0, stream, histf, histb, out);
}

// Round 3
// 5670.171 us; speedup vs baseline: 1.3253x; 1.3253x over previous
//
#include <hip/hip_runtime.h>
#include <stdint.h>

#define T_LEN 1024
#define BATCH 32
#define DIN   512
#define HID   512
#define G3    1536          // 3*HID
#define ROWS  (T_LEN*BATCH) // 32768
#define NSL   8             // h-slices (blocks) per direction
#define FSTR  16            // flag stride in ints (64B cacheline)

typedef short bf16x8 __attribute__((ext_vector_type(8)));
typedef float f32x4  __attribute__((ext_vector_type(4)));
typedef uint32_t u32x4 __attribute__((ext_vector_type(4)));

__device__ __forceinline__ unsigned short f2bf(float f) {
  union { float f; uint32_t u; } v; v.f = f;
  uint32_t u = v.u;
  return (unsigned short)((u + 0x7fffu + ((u >> 16) & 1u)) >> 16);  // RNE
}
__device__ __forceinline__ float bf2f(unsigned short h) {
  union { uint32_t u; float f; } v; v.u = ((uint32_t)h) << 16; return v.f;
}
__device__ __forceinline__ float sigm(float x)   { return 1.f / (1.f + __expf(-x)); }
__device__ __forceinline__ float tanh_f(float x) { return 2.f / (1.f + __expf(-2.f * x)) - 1.f; }

// ---------------- zero init (stats + flags) ----------------
__global__ void zero_init(float* stats, int* flags) {
  int i = blockIdx.x * 256 + threadIdx.x;     // grid 1024 -> 262144 threads
  flags[i] = 0;                               // 2*1024*8*16 = 262144 ints
  if (i < 2 * G3) stats[i] = 0.f;
}

// ---------------- f32 -> bf16 convert ----------------
__global__ void convert_bf16(const float* __restrict__ src, unsigned short* __restrict__ dst, int n4) {
  int i = blockIdx.x * 256 + threadIdx.x;
  if (i < n4) {
    float4 v = ((const float4*)src)[i];
    ushort4 o;
    o.x = f2bf(v.x); o.y = f2bf(v.y); o.z = f2bf(v.z); o.w = f2bf(v.w);
    ((ushort4*)dst)[i] = o;
  }
}

// ---------------- P = x @ Wx^T  (bf16 in, bf16 out, fp32 acc) ----------------
__global__ __launch_bounds__(256) void gemm_proj(const unsigned short* __restrict__ xb,
                                                 const unsigned short* __restrict__ wxb,
                                                 unsigned short* __restrict__ P) {
  int w = threadIdx.x >> 6;
  int l = threadIdx.x & 63;
  int mi = w >> 1, ni = w & 1;
  int row_base = blockIdx.x * 64 + mi * 32;
  int col_base = blockIdx.y * 64 + ni * 32;
  int lr = l & 15, lk8 = (l >> 4) * 8;
  f32x4 acc00 = {0,0,0,0}, acc01 = {0,0,0,0}, acc10 = {0,0,0,0}, acc11 = {0,0,0,0};
  #pragma unroll 4
  for (int kk = 0; kk < 16; ++kk) {
    int k0 = kk * 32 + lk8;
    bf16x8 a0 = *(const bf16x8*)(xb  + (size_t)(row_base + lr) * DIN + k0);
    bf16x8 a1 = *(const bf16x8*)(xb  + (size_t)(row_base + 16 + lr) * DIN + k0);
    bf16x8 b0 = *(const bf16x8*)(wxb + (size_t)(col_base + lr) * DIN + k0);
    bf16x8 b1 = *(const bf16x8*)(wxb + (size_t)(col_base + 16 + lr) * DIN + k0);
    acc00 = __builtin_amdgcn_mfma_f32_16x16x32_bf16(a0, b0, acc00, 0, 0, 0);
    acc01 = __builtin_amdgcn_mfma_f32_16x16x32_bf16(a0, b1, acc01, 0, 0, 0);
    acc10 = __builtin_amdgcn_mfma_f32_16x16x32_bf16(a1, b0, acc10, 0, 0, 0);
    acc11 = __builtin_amdgcn_mfma_f32_16x16x32_bf16(a1, b1, acc11, 0, 0, 0);
  }
  int rrow = (l >> 4) * 4;
  #pragma unroll
  for (int r = 0; r < 4; ++r) {
    P[(size_t)(row_base +      rrow + r) * G3 + col_base +      lr] = f2bf(acc00[r]);
    P[(size_t)(row_base +      rrow + r) * G3 + col_base + 16 + lr] = f2bf(acc01[r]);
    P[(size_t)(row_base + 16 + rrow + r) * G3 + col_base +      lr] = f2bf(acc10[r]);
    P[(size_t)(row_base + 16 + rrow + r) * G3 + col_base + 16 + lr] = f2bf(acc11[r]);
  }
}

// ---------------- per-channel sums over rows ----------------
__global__ void bn_stats(const unsigned short* __restrict__ P, float* __restrict__ stats) {
  int col = blockIdx.x * 256 + threadIdx.x;   // grid.x = 6  -> 1536 cols
  int r0  = blockIdx.y * 512;                 // grid.y = 64 -> 32768 rows
  float s = 0.f, q = 0.f;
  for (int r = 0; r < 512; ++r) {
    float v = bf2f(P[(size_t)(r0 + r) * G3 + col]);
    s += v; q += v * v;
  }
  atomicAdd(&stats[col], s);
  atomicAdd(&stats[G3 + col], q);
}

// ---------------- fold BN into scale/shift ----------------
__global__ void bn_final(const float* __restrict__ stats, const float* __restrict__ gamma,
                         const float* __restrict__ beta, float* __restrict__ params) {
  int c = blockIdx.x * 256 + threadIdx.x;
  if (c >= G3) return;
  float mean = stats[c] * (1.f / ROWS);
  float var  = stats[G3 + c] * (1.f / ROWS) - mean * mean;
  float sc = gamma[c] * rsqrtf(var + 1e-5f);
  params[c] = sc;
  params[G3 + c] = beta[c] - mean * sc;
}

// ---------------- the bidirectional GRU scan ----------------
// 16 blocks: [0,8) fwd, [8,16) bwd. Block owns h-cols [s*64, s*64+64).
// ALL cross-block traffic (h history, flags) uses sc0|sc1 cache-bypass
// (write-through to the coherent L3) -> zero buffer_inv / buffer_wbl2 in
// the loop. Ordering via raw s_waitcnt vmcnt(0).
__global__ __launch_bounds__(256, 1) void scan_kernel(
    const unsigned short* __restrict__ P, const float* __restrict__ params,
    const unsigned short* __restrict__ whf, const unsigned short* __restrict__ whb,
    unsigned short* __restrict__ histf, unsigned short* __restrict__ histb,
    int* __restrict__ flags) {
  int blk = blockIdx.x;
  int d = blk >> 3;          // direction
  int s = blk & 7;           // slice
  int j0 = s * 64;           // first owned h column
  int tid = threadIdx.x;
  int w = tid >> 6, l = tid & 63;
  int lr = l & 15, lk8 = (l >> 4) * 8;

  const unsigned short* wh = d ? whb : whf;
  unsigned short* myhist = d ? histb : histf;
  int* myflags = flags + (size_t)d * T_LEN * NSL * FSTR;

  // B fragments: wave w owns hp-col tiles i = w*3+q (q=0..2);
  // tile i -> gate g = i>>2, sub n = i&3, cols cb = g*512 + j0 + n*16.
  bf16x8 bfrag[3][16];
  #pragma unroll
  for (int q = 0; q < 3; ++q) {
    int i = w * 3 + q;
    int cb = (i >> 2) * HID + j0 + (i & 3) * 16;
    const unsigned short* wrow = wh + (size_t)(cb + lr) * HID;
    #pragma unroll
    for (int kk = 0; kk < 16; ++kk)
      bfrag[q][kk] = *(const bf16x8*)(wrow + kk * 32 + lk8);
  }

  __shared__ __align__(16) char hlds[BATCH * HID * 2];  // 32 KB XOR-swizzled h_prev
  __shared__ float hp[3][BATCH][66];                    // padded vs bank conflicts

  // epilogue mapping: thread -> column PAIR jc0 = j0 + 2*(tid&31), batches (tid>>5)+i*8
  int jp = tid & 31;
  int jc0 = j0 + jp * 2;
  float scr[2], shr[2], scz[2], shz[2], scn[2], shn[2];
  #pragma unroll
  for (int u = 0; u < 2; ++u) {
    int c = jc0 + u;
    scr[u] = params[c];           shr[u] = params[G3 + c];
    scz[u] = params[HID + c];     shz[u] = params[G3 + HID + c];
    scn[u] = params[2 * HID + c]; shn[u] = params[G3 + 2 * HID + c];
  }

  for (int t = 0; t < T_LEN; ++t) {
    int time = d ? (T_LEN - 1 - t) : t;

    // ---- prefetch this step's x-projection values (h-independent) ----
    uint32_t pr[4], pz[4], pn[4];
    #pragma unroll
    for (int i = 0; i < 4; ++i) {
      int b = (tid >> 5) + i * 8;
      const unsigned short* prow = P + (size_t)(time * BATCH + b) * G3 + jc0;
      pr[i] = *(const uint32_t*)(prow);
      pz[i] = *(const uint32_t*)(prow + HID);
      pn[i] = *(const uint32_t*)(prow + 2 * HID);
    }

    // ---- wait for all 8 producer flags of step t-1, stage h from L3 ----
    if (t > 0) {
      if (tid < NSL) {
        const int* fa = myflags + (size_t)(t - 1) * NSL * FSTR + tid * FSTR;
        int guard = 0, fv = 0;
        do {
          asm volatile("global_load_dword %0, %1, off sc0 sc1\n\ts_waitcnt vmcnt(0)"
                       : "=v"(fv) : "v"(fa) : "memory");
          if (++guard > (1 << 17)) break;   // bailout: wrong answer beats a hang
        } while (fv == 0);
      }
      __syncthreads();
      const char* hprev = (const char*)(myhist + (size_t)(t - 1) * BATCH * HID);
      u32x4 hv[8];
      #pragma unroll
      for (int i = 0; i < 8; ++i) {
        const char* a = hprev + (tid + i * 256) * 16;
        asm volatile("global_load_dwordx4 %0, %1, off sc0 sc1" : "=v"(hv[i]) : "v"(a));
      }
      asm volatile("s_waitcnt vmcnt(0)" ::: "memory");
      __builtin_amdgcn_sched_barrier(0);
      #pragma unroll
      for (int i = 0; i < 8; ++i) {
        int c = tid + i * 256;              // 2048 chunks of 16B
        int row = c >> 6;
        *(u32x4*)(hlds + ((c * 16) ^ ((row & 7) << 4))) = hv[i];
      }
    } else {
      u32x4 z = {0, 0, 0, 0};
      #pragma unroll
      for (int i = 0; i < 8; ++i) {
        int c = tid + i * 256;
        *(u32x4*)(hlds + c * 16) = z;
      }
    }
    __syncthreads();

    // ---- hp = h_prev @ Wh_slice^T : M=32, N=48/wave, K=512 ----
    f32x4 acc[2][3] = {};
    #pragma unroll
    for (int kk = 0; kk < 16; ++kk) {
      int cbase = kk * 64 + lk8 * 2;
      int sw = (lr & 7) << 4;               // (lr+16)&7 == lr&7
      bf16x8 a0 = *(const bf16x8*)(hlds + ((lr * 1024 + cbase) ^ sw));
      bf16x8 a1 = *(const bf16x8*)(hlds + (((lr + 16) * 1024 + cbase) ^ sw));
      #pragma unroll
      for (int q = 0; q < 3; ++q) {
        acc[0][q] = __builtin_amdgcn_mfma_f32_16x16x32_bf16(a0, bfrag[q][kk], acc[0][q], 0, 0, 0);
        acc[1][q] = __builtin_amdgcn_mfma_f32_16x16x32_bf16(a1, bfrag[q][kk], acc[1][q], 0, 0, 0);
      }
    }
    // D layout: row = (l>>4)*4 + r, col = l&15
    #pragma unroll
    for (int q = 0; q < 3; ++q) {
      int i = w * 3 + q;
      int g = i >> 2, ncol = (i & 3) * 16 + lr;
      #pragma unroll
      for (int m = 0; m < 2; ++m) {
        int rrow = m * 16 + (l >> 4) * 4;
        #pragma unroll
        for (int r = 0; r < 4; ++r) hp[g][rrow + r][ncol] = acc[m][q][r];
      }
    }
    __syncthreads();

    // ---- gates + h update: 2 cols x 4 batches per thread, write-through ----
    unsigned short* hout = myhist + (size_t)t * BATCH * HID;
    #pragma unroll
    for (int i = 0; i < 4; ++i) {
      int b = (tid >> 5) + i * 8;
      float2 rp2 = *(const float2*)&hp[0][b][2 * jp];
      float2 zp2 = *(const float2*)&hp[1][b][2 * jp];
      float2 np2 = *(const float2*)&hp[2][b][2 * jp];
      uint32_t hpair = *(const uint32_t*)(hlds + ((b * 1024 + jc0 * 2) ^ ((b & 7) << 4)));
      uint32_t o = 0;
      #pragma unroll
      for (int u = 0; u < 2; ++u) {
        float xrv = bf2f((unsigned short)((u ? (pr[i] >> 16) : pr[i]) & 0xffff));
        float xzv = bf2f((unsigned short)((u ? (pz[i] >> 16) : pz[i]) & 0xffff));
        float xnv = bf2f((unsigned short)((u ? (pn[i] >> 16) : pn[i]) & 0xffff));
        float rpv = u ? rp2.y : rp2.x;
        float zpv = u ? zp2.y : zp2.x;
        float npv = u ? np2.y : np2.x;
        float rv = sigm(fmaf(xrv, scr[u], shr[u]) + rpv);
        float zv = sigm(fmaf(xzv, scz[u], shz[u]) + zpv);
        float nv = tanh_f(fmaf(xnv, scn[u], shn[u]) + rv * npv);
        float hold = bf2f((unsigned short)((u ? (hpair >> 16) : hpair) & 0xffff));
        unsigned short ho = f2bf((1.f - zv) * hold + zv * nv);
        o |= ((uint32_t)ho) << (16 * u);
      }
      char* addr = (char*)(hout + (size_t)b * HID + jc0);
      asm volatile("global_store_dword %0, %1, off sc0 sc1" :: "v"(addr), "v"(o) : "memory");
    }
    asm volatile("s_waitcnt vmcnt(0)" ::: "memory");   // h at L3 before barrier
    __syncthreads();
    if (tid == 0) {
      int* fa = myflags + (size_t)t * NSL * FSTR + s * FSTR;
      int one = 1;
      asm volatile("global_store_dword %0, %1, off sc0 sc1" :: "v"(fa), "v"(one) : "memory");
    }
  }
}

// ---------------- out[t] = fwd[t] + bwd[T-1-t] ----------------
__global__ void final_add(const unsigned short* __restrict__ histf,
                          const unsigned short* __restrict__ histb,
                          float* __restrict__ out) {
  size_t i4 = (size_t)blockIdx.x * 256 + threadIdx.x;
  size_t e = i4 * 4;
  int t = (int)(e / (BATCH * HID));
  size_t rem = e % (BATCH * HID);
  ushort4 vf = *(const ushort4*)(histf + e);
  ushort4 vb = *(const ushort4*)(histb + (size_t)(T_LEN - 1 - t) * BATCH * HID + rem);
  float4 o;
  o.x = bf2f(vf.x) + bf2f(vb.x);
  o.y = bf2f(vf.y) + bf2f(vb.y);
  o.z = bf2f(vf.z) + bf2f(vb.z);
  o.w = bf2f(vf.w) + bf2f(vb.w);
  *(float4*)(out + e) = o;
}

extern "C" void kernel_launch(void* const* d_in, const int* in_sizes, int n_in,
                              void* d_out, int out_size, void* d_ws, size_t ws_size,
                              hipStream_t stream) {
  const float* x     = (const float*)d_in[0];
  const float* Wx    = (const float*)d_in[1];
  const float* Whf   = (const float*)d_in[2];
  const float* Whb   = (const float*)d_in[3];
  const float* gamma = (const float*)d_in[4];
  const float* beta  = (const float*)d_in[5];
  float* out = (float*)d_out;

  char* ws = (char*)d_ws;
  size_t off = 0;
  auto alloc = [&](size_t bytes) {
    char* p = ws + off;
    off += (bytes + 255) & ~(size_t)255;
    return p;
  };
  unsigned short* xb    = (unsigned short*)alloc((size_t)ROWS * DIN * 2);
  unsigned short* wxb   = (unsigned short*)alloc((size_t)G3 * DIN * 2);
  unsigned short* whfb  = (unsigned short*)alloc((size_t)G3 * HID * 2);
  unsigned short* whbb  = (unsigned short*)alloc((size_t)G3 * HID * 2);
  unsigned short* P     = (unsigned short*)alloc((size_t)ROWS * G3 * 2);
  float* stats          = (float*)alloc(2 * G3 * 4);
  float* params         = (float*)alloc(2 * G3 * 4);
  unsigned short* histf = (unsigned short*)alloc((size_t)T_LEN * BATCH * HID * 2);
  unsigned short* histb = (unsigned short*)alloc((size_t)T_LEN * BATCH * HID * 2);
  int* flags            = (int*)alloc((size_t)2 * T_LEN * NSL * FSTR * 4);

  hipLaunchKernelGGL(zero_init, dim3(1024), dim3(256), 0, stream, stats, flags);
  hipLaunchKernelGGL(convert_bf16, dim3(16384), dim3(256), 0, stream, x, xb, ROWS * DIN / 4);
  hipLaunchKernelGGL(convert_bf16, dim3(768), dim3(256), 0, stream, Wx, wxb, G3 * DIN / 4);
  hipLaunchKernelGGL(convert_bf16, dim3(768), dim3(256), 0, stream, Whf, whfb, G3 * HID / 4);
  hipLaunchKernelGGL(convert_bf16, dim3(768), dim3(256), 0, stream, Whb, whbb, G3 * HID / 4);
  hipLaunchKernelGGL(gemm_proj, dim3(512, 24), dim3(256), 0, stream, xb, wxb, P);
  hipLaunchKernelGGL(bn_stats, dim3(6, 64), dim3(256), 0, stream, P, stats);
  hipLaunchKernelGGL(bn_final, dim3(6), dim3(256), 0, stream, stats, gamma, beta, params);
  hipLaunchKernelGGL(scan_kernel, dim3(16), dim3(256), 0, stream,
                     P, params, whfb, whbb, histf, histb, flags);
  hipLaunchKernelGGL(final_add, dim3(16384), dim3(256), 0, stream, histf, histb, out);
}